// Round 4
// baseline (938.200 us; speedup 1.0000x reference)
//
// Round 6: fused gemm_ln kernel — Wo-GEMM+residual+LN1 and FF2-GEMM+residual+LN2
// each become ONE kernel (block owns 16 full rows; LN is block-local via LDS Y
// tile + 16-lane shfl tree). Eliminates 8 resid_ln launches and the attn_out/ff2
// fp32 round-trips (128 MB HBM total). QKV/FF1 keep the 2-phase prefetch gemm_bt.
#include <hip/hip_runtime.h>
#include <hip/hip_bf16.h>

#define B_ 8
#define L_ 512
#define D_ 512
#define H_ 8
#define F_ 2048
#define NL_ 4
#define BL 4096            // B_*L_
#define EPS_ 1e-5f

typedef __bf16 bf16_t;
typedef bf16_t bf16x8 __attribute__((ext_vector_type(8)));
typedef float f32x4 __attribute__((ext_vector_type(4)));
typedef unsigned short u16x4 __attribute__((ext_vector_type(4)));

__device__ __forceinline__ unsigned short f2b_rn(float f) {
  unsigned u = __builtin_bit_cast(unsigned, f);
  u = (u + 0x7fffu + ((u >> 16) & 1u)) >> 16;
  return (unsigned short)u;
}

// async global->LDS, 16B per lane. LDS dest must be wave-uniform base + lane*16.
__device__ __forceinline__ void gload_lds16(const unsigned short* g, unsigned short* l) {
  __builtin_amdgcn_global_load_lds(
      (const __attribute__((address_space(1))) void*)g,
      (__attribute__((address_space(3))) void*)l, 16, 0, 0);
}

// C[M,N] = relu?(scale * A[M,K] @ B[N,K]^T + bias[N]); optional fp32 and bf16 outputs.
// 2-phase pipeline: double-buffered LDS, next tile staged before current compute,
// single __syncthreads per K-step. XCD-aware swizzle when gridX%8==0 and z==1.
template<int BM, int BN, int MT, int NT>
__global__ __launch_bounds__(256)
void gemm_bt(const unsigned short* __restrict__ A, int lda, long sAo, long sAi,
             const unsigned short* __restrict__ Bm, int ldb, long sBo, long sBi,
             float* __restrict__ Cf, unsigned short* __restrict__ Cb, int ldc,
             long sCo, long sCi,
             const float* __restrict__ bias, int K, float scale, int relu, int zi)
{
  static_assert(BM == MT * 32 && BN == NT * 32, "waves are 2x2");
  __shared__ unsigned short As[2][BM * 32];
  __shared__ unsigned short Bs[2][BN * 32];
  const int tid  = threadIdx.x;
  const int lane = tid & 63;
  const int wave = tid >> 6;
  const int wm = (wave >> 1) * (MT * 16);
  const int wn = (wave & 1) * (NT * 16);
  int bx = blockIdx.x, by = blockIdx.y;
  if (gridDim.z == 1 && (gridDim.x & 7) == 0) {
    const int gx = gridDim.x, cx = gx >> 3;
    const int lid = by * gx + bx;
    const int xcd = lid & 7;
    const int t = lid >> 3;
    bx = xcd * cx + (t % cx);
    by = t / cx;
  }
  const int m0 = bx * BM;
  const int n0 = by * BN;
  const int z  = blockIdx.z;
  const long offA = (long)(z / zi) * sAo + (long)(z % zi) * sAi;
  const long offB = (long)(z / zi) * sBo + (long)(z % zi) * sBi;
  const long offC = (long)(z / zi) * sCo + (long)(z % zi) * sCi;

  const unsigned short* Ab = A + offA + (long)m0 * lda;
  const unsigned short* Bb = Bm + offB + (long)n0 * ldb;

  auto stage = [&](int buf, int k0) {
#pragma unroll
    for (int j = 0; j < BM / 64; ++j) {
      int c = tid + j * 256;
      int r = c >> 2, cc = (c & 3) * 8;
      gload_lds16(Ab + (long)r * lda + (k0 + cc), &As[buf][c * 8]);
    }
#pragma unroll
    for (int j = 0; j < BN / 64; ++j) {
      int c = tid + j * 256;
      int r = c >> 2, cc = (c & 3) * 8;
      gload_lds16(Bb + (long)r * ldb + (k0 + cc), &Bs[buf][c * 8]);
    }
  };

  f32x4 acc[MT][NT] = {};

  stage(0, 0);
  __syncthreads();
  int cur = 0;
  for (int k0 = 0; k0 < K; k0 += 32) {
    if (k0 + 32 < K) stage(cur ^ 1, k0 + 32);   // prefetch next tile (async)
    bf16x8 af[MT], bfr[NT];
#pragma unroll
    for (int mt = 0; mt < MT; ++mt)
      af[mt] = *(const bf16x8*)(&As[cur][(wm + mt * 16 + (lane & 15)) * 32 + (lane >> 4) * 8]);
#pragma unroll
    for (int nt = 0; nt < NT; ++nt)
      bfr[nt] = *(const bf16x8*)(&Bs[cur][(wn + nt * 16 + (lane & 15)) * 32 + (lane >> 4) * 8]);
#pragma unroll
    for (int mt = 0; mt < MT; ++mt)
#pragma unroll
      for (int nt = 0; nt < NT; ++nt)
        acc[mt][nt] = __builtin_amdgcn_mfma_f32_16x16x32_bf16(af[mt], bfr[nt], acc[mt][nt], 0, 0, 0);
    __syncthreads();   // drains prefetch (overlapped with MFMA) + guards buffer swap
    cur ^= 1;
  }

  // C/D layout: col=lane&15, row=(lane>>4)*4+r
#pragma unroll
  for (int nt = 0; nt < NT; ++nt) {
    const int col = n0 + wn + nt * 16 + (lane & 15);
    const float bb = bias ? bias[col] : 0.f;
#pragma unroll
    for (int mt = 0; mt < MT; ++mt) {
#pragma unroll
      for (int r = 0; r < 4; ++r) {
        const int row = m0 + wm + mt * 16 + (lane >> 4) * 4 + r;
        float v = acc[mt][nt][r] * scale + bb;
        if (relu) v = fmaxf(v, 0.f);
        const long o = offC + (long)row * ldc + col;
        if (Cf) Cf[o] = v;
        if (Cb) Cb[o] = f2b_rn(v);
      }
    }
  }
}

// Fused GEMM + residual + LayerNorm over full rows:
//   out = LN(res + A[16rows,K] @ Bw[512,K]^T + bias) * g + be   (fp32 + bf16 out)
// 256 blocks of 16 rows; 4 waves, wave w owns cols [w*128,(w+1)*128) (NT=8).
// 2-phase BK=32 pipeline; acc -> LDS Y tile -> block-local LN (16-lane shfl tree).
__global__ __launch_bounds__(256)
void gemm_ln(const unsigned short* __restrict__ A, int lda,
             const unsigned short* __restrict__ Bw,
             const float* __restrict__ res,
             const float* __restrict__ bias,
             const float* __restrict__ g, const float* __restrict__ be,
             float* __restrict__ outf, unsigned short* __restrict__ outb,
             int K)
{
  __shared__ __align__(16) unsigned short As[2][16 * 32];   // 1 KB each
  __shared__ __align__(16) unsigned short Bs[2][512 * 32];  // 32 KB each
  __shared__ __align__(16) float Y[16 * 512];               // 32 KB
  const int tid = threadIdx.x, lane = tid & 63, wave = tid >> 6;
  const int lo4 = lane & 15, hi4 = lane >> 4;
  // XCD swizzle: 256 blocks -> XCD x owns contiguous M-chunk of 32 blocks.
  const int bx = (blockIdx.x & 7) * 32 + (blockIdx.x >> 3);
  const int m0 = bx * 16;
  const unsigned short* Ab = A + (long)m0 * lda;

  auto stage = [&](int buf, int k0) {
    if (wave == 0)   // A tile is 1KB = exactly one wave's 64x16B
      gload_lds16(Ab + (long)(lane >> 2) * lda + (k0 + (lane & 3) * 8), &As[buf][lane * 8]);
#pragma unroll
    for (int j = 0; j < 8; ++j) {           // B tile 512x32 = 32KB
      int c = tid + j * 256;
      int r = c >> 2, cc = (c & 3) * 8;
      gload_lds16(Bw + (long)r * K + (k0 + cc), &Bs[buf][c * 8]);
    }
  };

  f32x4 acc[8] = {};
  stage(0, 0);
  __syncthreads();
  int cur = 0;
  for (int k0 = 0; k0 < K; k0 += 32) {
    if (k0 + 32 < K) stage(cur ^ 1, k0 + 32);
    const bf16x8 af = *(const bf16x8*)&As[cur][lo4 * 32 + hi4 * 8];
#pragma unroll
    for (int nt = 0; nt < 8; ++nt) {
      const bf16x8 bfr = *(const bf16x8*)&Bs[cur][(wave * 128 + nt * 16 + lo4) * 32 + hi4 * 8];
      acc[nt] = __builtin_amdgcn_mfma_f32_16x16x32_bf16(af, bfr, acc[nt], 0, 0, 0);
    }
    __syncthreads();
    cur ^= 1;
  }

  // acc -> Y[row][col]; MFMA C layout: col = wave*128+nt*16+lo4, row = hi4*4+r.
#pragma unroll
  for (int nt = 0; nt < 8; ++nt) {
    const int col = wave * 128 + nt * 16 + lo4;
#pragma unroll
    for (int r = 0; r < 4; ++r)
      Y[(hi4 * 4 + r) * 512 + col] = acc[nt][r];
  }
  __syncthreads();

  // LN pass: thread t -> row = t>>4, 8 strided f32x4 chunks at col = (t&15)*4+j*64
  // (strided mapping keeps LDS reads spread over 8 bank-groups = b128-optimal).
  const int row = tid >> 4, c16 = tid & 15;
  const long grow = (long)(m0 + row) * 512;
  f32x4 v[8];
  float s = 0.f, s2 = 0.f;
#pragma unroll
  for (int j = 0; j < 8; ++j) {
    const int col = c16 * 4 + j * 64;
    const f32x4 yv = *(const f32x4*)&Y[row * 512 + col];
    const f32x4 bb = *(const f32x4*)&bias[col];
    const f32x4 rr = *(const f32x4*)&res[grow + col];
    f32x4 t4;
#pragma unroll
    for (int i = 0; i < 4; ++i) {
      t4[i] = yv[i] + bb[i] + rr[i];
      s += t4[i];
      s2 += t4[i] * t4[i];
    }
    v[j] = t4;
  }
  // reduce over the 16 threads of this row (contiguous 16-lane group)
#pragma unroll
  for (int msk = 1; msk < 16; msk <<= 1) {
    s  += __shfl_xor(s, msk);
    s2 += __shfl_xor(s2, msk);
  }
  const float mu  = s * (1.f / 512.f);
  const float var = s2 * (1.f / 512.f) - mu * mu;
  const float ri  = rsqrtf(var + EPS_);
#pragma unroll
  for (int j = 0; j < 8; ++j) {
    const int col = c16 * 4 + j * 64;
    const f32x4 vg = *(const f32x4*)&g[col];
    const f32x4 ve = *(const f32x4*)&be[col];
    f32x4 y;
    u16x4 yb;
#pragma unroll
    for (int i = 0; i < 4; ++i) {
      y[i] = (v[j][i] - mu) * ri * vg[i] + ve[i];
      yb[i] = f2b_rn(y[i]);
    }
    *(f32x4*)&outf[grow + col] = y;
    *(u16x4*)&outb[grow + col] = yb;
  }
}

// Fused attention, swapped operands. Per (64-row q-block, z=(b*8+h)):
//   scores^T = mfma(K,Q) -> scalar softmax (lane owns one q-row) -> P (bf16) into
//   LDS + V^T into LDS -> barrier -> coalesced f32x4 nontemporal attn stores
//   (AFTER the barrier: drain overlaps PV) -> ctx^T = mfma(V^T,P) -> u16x4 ctx.
__global__ __launch_bounds__(256)
void attn_fused(const unsigned short* __restrict__ qkv,
                float* __restrict__ attnf,
                unsigned short* __restrict__ ctxb) {
  __shared__ __align__(16) unsigned short Qs[64 * 64];    // 8 KB, linear
  __shared__ __align__(16) unsigned short KP[512 * 64];   // 64 KB: K (src-preswizzled) then P (swizzled)
  __shared__ __align__(16) unsigned short VT[64 * 512];   // 64 KB: V^T (swizzled)
  const int tid = threadIdx.x, lane = tid & 63, wave = tid >> 6;
  const int lo4 = lane & 15, hi4 = lane >> 4;
  // XCD remap: each XCD owns 8 consecutive (b,h) groups -> K/V L2-resident.
  int bxr = blockIdx.x, byr = blockIdx.y;
  {
    const int lid = byr * 8 + bxr;           // grid is (8, 64)
    const int xcd = lid & 7;
    const int t = lid >> 3;                  // [0,64)
    byr = xcd * 8 + (t & 7);
    bxr = t >> 3;
  }
  const int q0 = bxr * 64;
  const int z = byr, b = z >> 3, h = z & 7;
  const unsigned short* qbase = qkv + (long)b * 512 * 1536 + h * 64;
  const unsigned short* kbase = qbase + 512;
  const unsigned short* vbase = qbase + 1024;

  // V prefetch into regs: 16 x 16B per thread (drained by barrier-1 vmcnt(0)).
  bf16x8 vreg[16];
#pragma unroll
  for (int j = 0; j < 16; ++j) {
    const int d8 = j >> 1;
    const int s = (j & 1) * 256 + tid;
    vreg[j] = *(const bf16x8*)(vbase + (long)s * 1536 + d8 * 8);
  }

  // stage Q [64,64] linear
#pragma unroll
  for (int j = 0; j < 2; ++j) {
    int c = tid + j * 256;
    int r = c >> 3, cc = (c & 7) * 8;
    gload_lds16(qbase + (long)(q0 + r) * 1536 + cc, &Qs[c * 8]);
  }
  // stage K [512,64] with pre-swizzled SOURCE (linear LDS dest + swizzled read)
#pragma unroll
  for (int j = 0; j < 16; ++j) {
    int c = tid + j * 256;
    int r = c >> 3, ch = (c & 7) ^ (r & 7);
    gload_lds16(kbase + (long)r * 1536 + ch * 8, &KP[c * 8]);
  }
  __syncthreads();

  // Q fragments (B operand): row n = q = wave*16 + lo4
  const bf16x8 qf0 = *(const bf16x8*)&Qs[(wave * 16 + lo4) * 64 + hi4 * 8];
  const bf16x8 qf1 = *(const bf16x8*)&Qs[(wave * 16 + lo4) * 64 + 32 + hi4 * 8];

  // scores^T: acc[st] holds col=q (this lane's row), row = s = st*16 + hi4*4 + r
  f32x4 acc[32];
#pragma unroll
  for (int st = 0; st < 32; ++st) {
    const int n = st * 16 + lo4;
    const int sw = lo4 & 7;
    f32x4 a = {};
    const bf16x8 k0f = *(const bf16x8*)&KP[n * 64 + ((hi4 ^ sw) * 8)];
    const bf16x8 k1f = *(const bf16x8*)&KP[n * 64 + (((hi4 + 4) ^ sw) * 8)];
    a = __builtin_amdgcn_mfma_f32_16x16x32_bf16(k0f, qf0, a, 0, 0, 0);
    a = __builtin_amdgcn_mfma_f32_16x16x32_bf16(k1f, qf1, a, 0, 0, 0);
    acc[st] = a;
  }

  // scalar row softmax: this lane's q-row is spread over hi4 groups (shfl 16,32)
  float mx = -1e30f;
#pragma unroll
  for (int st = 0; st < 32; ++st)
#pragma unroll
    for (int r = 0; r < 4; ++r) {
      acc[st][r] *= 0.125f;
      mx = fmaxf(mx, acc[st][r]);
    }
  mx = fmaxf(mx, __shfl_xor(mx, 16));
  mx = fmaxf(mx, __shfl_xor(mx, 32));
  float sm = 0.f;
#pragma unroll
  for (int st = 0; st < 32; ++st)
#pragma unroll
    for (int r = 0; r < 4; ++r) {
      const float e = __expf(acc[st][r] - mx);
      acc[st][r] = e;
      sm += e;
    }
  sm += __shfl_xor(sm, 16);
  sm += __shfl_xor(sm, 32);
  const float inv = 1.f / sm;

  __syncthreads();   // all waves done reading K tile; KP becomes the P buffer

  // V^T into LDS, swizzled (element idx ^ ((d&7)<<3)).
#pragma unroll
  for (int j = 0; j < 16; ++j) {
    const int d8 = j >> 1;
    const int s = (j & 1) * 256 + tid;
#pragma unroll
    for (int jj = 0; jj < 8; ++jj) {
      const int d = d8 * 8 + jj;
      VT[(d * 512 + s) ^ ((d & 7) << 3)] = ((const unsigned short*)&vreg[j])[jj];
    }
  }

  // normalize P in regs; bf16 P -> LDS (b64). Global stores deferred past barrier.
  const int q = wave * 16 + lo4;
#pragma unroll
  for (int st = 0; st < 32; ++st) {
    u16x4 pb;
#pragma unroll
    for (int r = 0; r < 4; ++r) {
      acc[st][r] *= inv;
      pb[r] = f2b_rn(acc[st][r]);
    }
    *(u16x4*)&KP[(q * 512 + st * 16 + hi4 * 4) ^ ((q & 7) << 3)] = pb;
  }
  __syncthreads();   // lgkm drain only matters; no outstanding global stores here

  // fp32 attn out now: stores drain under PV + next block's work, nothing waits.
  float* aout = attnf + (long)z * 262144 + (long)(q0 + q) * 512;
#pragma unroll
  for (int st = 0; st < 32; ++st)
    __builtin_nontemporal_store(acc[st], (f32x4*)(aout + st * 16 + hi4 * 4));

  // PV swapped: A = V^T (rows d), B = P (rows q) -> col=q, row=d.
  const int wq = (wave >> 1) * 32, wd = (wave & 1) * 32;
  f32x4 acc2[2][2] = {};
#pragma unroll
  for (int k0 = 0; k0 < 512; k0 += 32) {
    bf16x8 vf[2], pf[2];
#pragma unroll
    for (int mt = 0; mt < 2; ++mt) {
      const int d = wd + mt * 16 + lo4;
      vf[mt] = *(const bf16x8*)&VT[(d * 512 + k0 + hi4 * 8) ^ ((d & 7) << 3)];
    }
#pragma unroll
    for (int nt = 0; nt < 2; ++nt) {
      const int m = wq + nt * 16 + lo4;
      pf[nt] = *(const bf16x8*)&KP[(m * 512 + k0 + hi4 * 8) ^ ((m & 7) << 3)];
    }
#pragma unroll
    for (int mt = 0; mt < 2; ++mt)
#pragma unroll
      for (int nt = 0; nt < 2; ++nt)
        acc2[mt][nt] = __builtin_amdgcn_mfma_f32_16x16x32_bf16(vf[mt], pf[nt], acc2[mt][nt], 0, 0, 0);
  }

  // ctx write: col=q (lo4), row=d (hi4*4+r) -> u16x4 along d.
#pragma unroll
  for (int nt = 0; nt < 2; ++nt) {
    const int qq = q0 + wq + nt * 16 + lo4;
    unsigned short* cb = ctxb + ((long)(b * 512 + qq)) * 512 + h * 64;
#pragma unroll
    for (int mt = 0; mt < 2; ++mt) {
      u16x4 o;
#pragma unroll
      for (int r = 0; r < 4; ++r) o[r] = f2b_rn(acc2[mt][nt][r]);
      *(u16x4*)&cb[wd + mt * 16 + hi4 * 4] = o;
    }
  }
}

__global__ void f2b_arr(const float* __restrict__ in, unsigned short* __restrict__ out, long n4) {
  long i = (long)blockIdx.x * 256 + threadIdx.x;
  const long stride = (long)gridDim.x * 256;
  for (; i < n4; i += stride) {
    const f32x4 v = *(const f32x4*)&in[i * 4];
    u16x4 o;
#pragma unroll
    for (int k = 0; k < 4; ++k) o[k] = f2b_rn(v[k]);
    *(u16x4*)&out[i * 4] = o;
  }
}

__global__ void copy_conv(const float* __restrict__ in, float* __restrict__ outf,
                          unsigned short* __restrict__ outb, long n4) {
  long i = (long)blockIdx.x * 256 + threadIdx.x;
  const long stride = (long)gridDim.x * 256;
  for (; i < n4; i += stride) {
    const f32x4 v = *(const f32x4*)&in[i * 4];
    u16x4 o;
#pragma unroll
    for (int k = 0; k < 4; ++k) o[k] = f2b_rn(v[k]);
    *(f32x4*)&outf[i * 4] = v;
    *(u16x4*)&outb[i * 4] = o;
  }
}

extern "C" void kernel_launch(void* const* d_in, const int* in_sizes, int n_in,
                              void* d_out, int out_size, void* d_ws, size_t ws_size,
                              hipStream_t stream) {
  const float* src  = (const float*)d_in[0];
  const float* Wqkv = (const float*)d_in[1];
  const float* bqkv = (const float*)d_in[2];
  const float* Wo   = (const float*)d_in[3];
  const float* bo   = (const float*)d_in[4];
  const float* W1   = (const float*)d_in[5];
  const float* b1   = (const float*)d_in[6];
  const float* W2   = (const float*)d_in[7];
  const float* b2   = (const float*)d_in[8];
  const float* g1   = (const float*)d_in[9];
  const float* be1  = (const float*)d_in[10];
  const float* g2   = (const float*)d_in[11];
  const float* be2  = (const float*)d_in[12];

  char* p = (char*)d_ws;
  auto take = [&](size_t bytes) { void* r = (void*)p; p += (bytes + 255) & ~(size_t)255; return r; };
  float* x        = (float*)take((size_t)BL * 512 * 4);
  float* x1       = (float*)take((size_t)BL * 512 * 4);
  unsigned short* xbf    = (unsigned short*)take((size_t)BL * 512 * 2);
  unsigned short* qkvbf  = (unsigned short*)take((size_t)BL * 1536 * 2);
  unsigned short* ctxbf  = (unsigned short*)take((size_t)BL * 512 * 2);
  unsigned short* ff1bf  = (unsigned short*)take((size_t)BL * 2048 * 2);
  unsigned short* Wqkvb  = (unsigned short*)take((size_t)4 * 1536 * 512 * 2);
  unsigned short* Wob    = (unsigned short*)take((size_t)4 * 512 * 512 * 2);
  unsigned short* W1b    = (unsigned short*)take((size_t)4 * 2048 * 512 * 2);
  unsigned short* W2b    = (unsigned short*)take((size_t)4 * 512 * 2048 * 2);

  f2b_arr<<<1024, 256, 0, stream>>>(Wqkv, Wqkvb, 4L * 1536 * 512 / 4);
  f2b_arr<<<512,  256, 0, stream>>>(Wo,   Wob,   4L * 512 * 512 / 4);
  f2b_arr<<<1024, 256, 0, stream>>>(W1,   W1b,   4L * 2048 * 512 / 4);
  f2b_arr<<<1024, 256, 0, stream>>>(W2,   W2b,   4L * 512 * 2048 / 4);
  copy_conv<<<1024, 256, 0, stream>>>(src, x, xbf, (long)BL * 512 / 4);

  float* out_x    = (float*)d_out;
  float* out_attn = out_x + (size_t)BL * 512;

  for (int i = 0; i < NL_; ++i) {
    // QKV: [4096,1536] = x @ Wqkv^T + bqkv  (bf16 out); 64x128 tiles -> 768 blocks
    gemm_bt<64, 128, 2, 4><<<dim3(BL / 64, 1536 / 128, 1), 256, 0, stream>>>(
        xbf, 512, 0, 0, Wqkvb + (size_t)i * 1536 * 512, 512, 0, 0,
        nullptr, qkvbf, 1536, 0, 0, bqkv + (size_t)i * 1536, 512, 1.f, 0, 1);

    // fused scores+softmax+PV: fp32 attn -> d_out, ctx bf16 -> ctxbf
    float* attnL = out_attn + (size_t)i * 64 * 512 * 512;
    attn_fused<<<dim3(8, 64), 256, 0, stream>>>(qkvbf, attnL, ctxbf);

    // x1 = LN(x + ctx @ Wo^T + bo)   (fused gemm+residual+LN)
    gemm_ln<<<256, 256, 0, stream>>>(
        ctxbf, 512, Wob + (size_t)i * 512 * 512, x, bo + (size_t)i * 512,
        g1 + (size_t)i * 512, be1 + (size_t)i * 512, x1, xbf, 512);

    // ff1 = relu(x1 @ W1^T + b1)  (bf16)
    gemm_bt<128, 128, 4, 4><<<dim3(32, 16, 1), 256, 0, stream>>>(
        xbf, 512, 0, 0, W1b + (size_t)i * 2048 * 512, 512, 0, 0,
        nullptr, ff1bf, 2048, 0, 0, b1 + (size_t)i * 2048, 512, 1.f, 1, 1);

    // x = LN(x1 + ff1 @ W2^T + b2); final layer writes straight to d_out
    gemm_ln<<<256, 256, 0, stream>>>(
        ff1bf, 2048, W2b + (size_t)i * 512 * 2048, x1, b2 + (size_t)i * 512,
        g2 + (size_t)i * 512, be2 + (size_t)i * 512, (i == 3) ? out_x : x, xbf, 2048);
  }
}

// Round 5
// 790.136 us; speedup vs baseline: 1.1874x; 1.1874x over previous
//
// Round 7: REVERT gemm_ln fusion (R6 regression: 16-row blocks re-staged the whole
// B weight 256x -> 512MB L2 traffic for FF2). Back to R5 structure (2-phase GEMM,
// deferred-store attn) + wave-per-row resid_ln (no LDS/no barrier, grid 1024) and
// merged weight-conversion launch.
#include <hip/hip_runtime.h>
#include <hip/hip_bf16.h>

#define B_ 8
#define L_ 512
#define D_ 512
#define H_ 8
#define F_ 2048
#define NL_ 4
#define BL 4096            // B_*L_
#define EPS_ 1e-5f

typedef __bf16 bf16_t;
typedef bf16_t bf16x8 __attribute__((ext_vector_type(8)));
typedef float f32x4 __attribute__((ext_vector_type(4)));
typedef unsigned short u16x4 __attribute__((ext_vector_type(4)));

__device__ __forceinline__ unsigned short f2b_rn(float f) {
  unsigned u = __builtin_bit_cast(unsigned, f);
  u = (u + 0x7fffu + ((u >> 16) & 1u)) >> 16;
  return (unsigned short)u;
}

// async global->LDS, 16B per lane. LDS dest must be wave-uniform base + lane*16.
__device__ __forceinline__ void gload_lds16(const unsigned short* g, unsigned short* l) {
  __builtin_amdgcn_global_load_lds(
      (const __attribute__((address_space(1))) void*)g,
      (__attribute__((address_space(3))) void*)l, 16, 0, 0);
}

// C[M,N] = relu?(scale * A[M,K] @ B[N,K]^T + bias[N]); optional fp32 and bf16 outputs.
// Batched via blockIdx.z with (z/zi, z%zi) stride decomposition for A/B/C.
// XCD-aware swizzle (z==1, gridX%8==0): each XCD owns a contiguous M-chunk.
// 2-phase pipeline: double-buffered LDS, next tile staged before current compute,
// single __syncthreads per K-step (its vmcnt(0) drains loads that overlapped MFMA).
template<int BM, int BN, int MT, int NT>
__global__ __launch_bounds__(256)
void gemm_bt(const unsigned short* __restrict__ A, int lda, long sAo, long sAi,
             const unsigned short* __restrict__ Bm, int ldb, long sBo, long sBi,
             float* __restrict__ Cf, unsigned short* __restrict__ Cb, int ldc,
             long sCo, long sCi,
             const float* __restrict__ bias, int K, float scale, int relu, int zi)
{
  static_assert(BM == MT * 32 && BN == NT * 32, "waves are 2x2");
  __shared__ unsigned short As[2][BM * 32];
  __shared__ unsigned short Bs[2][BN * 32];
  const int tid  = threadIdx.x;
  const int lane = tid & 63;
  const int wave = tid >> 6;
  const int wm = (wave >> 1) * (MT * 16);
  const int wn = (wave & 1) * (NT * 16);
  int bx = blockIdx.x, by = blockIdx.y;
  if (gridDim.z == 1 && (gridDim.x & 7) == 0) {
    const int gx = gridDim.x, cx = gx >> 3;
    const int lid = by * gx + bx;
    const int xcd = lid & 7;
    const int t = lid >> 3;
    bx = xcd * cx + (t % cx);
    by = t / cx;
  }
  const int m0 = bx * BM;
  const int n0 = by * BN;
  const int z  = blockIdx.z;
  const long offA = (long)(z / zi) * sAo + (long)(z % zi) * sAi;
  const long offB = (long)(z / zi) * sBo + (long)(z % zi) * sBi;
  const long offC = (long)(z / zi) * sCo + (long)(z % zi) * sCi;

  const unsigned short* Ab = A + offA + (long)m0 * lda;
  const unsigned short* Bb = Bm + offB + (long)n0 * ldb;

  auto stage = [&](int buf, int k0) {
#pragma unroll
    for (int j = 0; j < BM / 64; ++j) {
      int c = tid + j * 256;
      int r = c >> 2, cc = (c & 3) * 8;
      gload_lds16(Ab + (long)r * lda + (k0 + cc), &As[buf][c * 8]);
    }
#pragma unroll
    for (int j = 0; j < BN / 64; ++j) {
      int c = tid + j * 256;
      int r = c >> 2, cc = (c & 3) * 8;
      gload_lds16(Bb + (long)r * ldb + (k0 + cc), &Bs[buf][c * 8]);
    }
  };

  f32x4 acc[MT][NT] = {};

  stage(0, 0);
  __syncthreads();
  int cur = 0;
  for (int k0 = 0; k0 < K; k0 += 32) {
    if (k0 + 32 < K) stage(cur ^ 1, k0 + 32);   // prefetch next tile (async)
    bf16x8 af[MT], bfr[NT];
#pragma unroll
    for (int mt = 0; mt < MT; ++mt)
      af[mt] = *(const bf16x8*)(&As[cur][(wm + mt * 16 + (lane & 15)) * 32 + (lane >> 4) * 8]);
#pragma unroll
    for (int nt = 0; nt < NT; ++nt)
      bfr[nt] = *(const bf16x8*)(&Bs[cur][(wn + nt * 16 + (lane & 15)) * 32 + (lane >> 4) * 8]);
#pragma unroll
    for (int mt = 0; mt < MT; ++mt)
#pragma unroll
      for (int nt = 0; nt < NT; ++nt)
        acc[mt][nt] = __builtin_amdgcn_mfma_f32_16x16x32_bf16(af[mt], bfr[nt], acc[mt][nt], 0, 0, 0);
    __syncthreads();   // drains prefetch (overlapped with MFMA) + guards buffer swap
    cur ^= 1;
  }

  // C/D layout: col=lane&15, row=(lane>>4)*4+r
#pragma unroll
  for (int nt = 0; nt < NT; ++nt) {
    const int col = n0 + wn + nt * 16 + (lane & 15);
    const float bb = bias ? bias[col] : 0.f;
#pragma unroll
    for (int mt = 0; mt < MT; ++mt) {
#pragma unroll
      for (int r = 0; r < 4; ++r) {
        const int row = m0 + wm + mt * 16 + (lane >> 4) * 4 + r;
        float v = acc[mt][nt][r] * scale + bb;
        if (relu) v = fmaxf(v, 0.f);
        const long o = offC + (long)row * ldc + col;
        if (Cf) Cf[o] = v;
        if (Cb) Cb[o] = f2b_rn(v);
      }
    }
  }
}

// Fused attention, swapped operands. Per (64-row q-block, z=(b*8+h)):
//   scores^T = mfma(K,Q) -> scalar softmax (lane owns one q-row) -> P (bf16) into
//   LDS + V^T into LDS -> barrier -> coalesced f32x4 nontemporal attn stores
//   (AFTER the barrier: drain overlaps PV) -> ctx^T = mfma(V^T,P) -> u16x4 ctx.
__global__ __launch_bounds__(256)
void attn_fused(const unsigned short* __restrict__ qkv,
                float* __restrict__ attnf,
                unsigned short* __restrict__ ctxb) {
  __shared__ __align__(16) unsigned short Qs[64 * 64];    // 8 KB, linear
  __shared__ __align__(16) unsigned short KP[512 * 64];   // 64 KB: K (src-preswizzled) then P (swizzled)
  __shared__ __align__(16) unsigned short VT[64 * 512];   // 64 KB: V^T (swizzled)
  const int tid = threadIdx.x, lane = tid & 63, wave = tid >> 6;
  const int lo4 = lane & 15, hi4 = lane >> 4;
  // XCD remap: each XCD owns 8 consecutive (b,h) groups -> K/V L2-resident.
  int bxr = blockIdx.x, byr = blockIdx.y;
  {
    const int lid = byr * 8 + bxr;           // grid is (8, 64)
    const int xcd = lid & 7;
    const int t = lid >> 3;                  // [0,64)
    byr = xcd * 8 + (t & 7);
    bxr = t >> 3;
  }
  const int q0 = bxr * 64;
  const int z = byr, b = z >> 3, h = z & 7;
  const unsigned short* qbase = qkv + (long)b * 512 * 1536 + h * 64;
  const unsigned short* kbase = qbase + 512;
  const unsigned short* vbase = qbase + 1024;

  // V prefetch into regs: 16 x 16B per thread (drained by barrier-1 vmcnt(0)).
  bf16x8 vreg[16];
#pragma unroll
  for (int j = 0; j < 16; ++j) {
    const int d8 = j >> 1;
    const int s = (j & 1) * 256 + tid;
    vreg[j] = *(const bf16x8*)(vbase + (long)s * 1536 + d8 * 8);
  }

  // stage Q [64,64] linear
#pragma unroll
  for (int j = 0; j < 2; ++j) {
    int c = tid + j * 256;
    int r = c >> 3, cc = (c & 7) * 8;
    gload_lds16(qbase + (long)(q0 + r) * 1536 + cc, &Qs[c * 8]);
  }
  // stage K [512,64] with pre-swizzled SOURCE (linear LDS dest + swizzled read)
#pragma unroll
  for (int j = 0; j < 16; ++j) {
    int c = tid + j * 256;
    int r = c >> 3, ch = (c & 7) ^ (r & 7);
    gload_lds16(kbase + (long)r * 1536 + ch * 8, &KP[c * 8]);
  }
  __syncthreads();

  // Q fragments (B operand): row n = q = wave*16 + lo4
  const bf16x8 qf0 = *(const bf16x8*)&Qs[(wave * 16 + lo4) * 64 + hi4 * 8];
  const bf16x8 qf1 = *(const bf16x8*)&Qs[(wave * 16 + lo4) * 64 + 32 + hi4 * 8];

  // scores^T: acc[st] holds col=q (this lane's row), row = s = st*16 + hi4*4 + r
  f32x4 acc[32];
#pragma unroll
  for (int st = 0; st < 32; ++st) {
    const int n = st * 16 + lo4;
    const int sw = lo4 & 7;
    f32x4 a = {};
    const bf16x8 k0f = *(const bf16x8*)&KP[n * 64 + ((hi4 ^ sw) * 8)];
    const bf16x8 k1f = *(const bf16x8*)&KP[n * 64 + (((hi4 + 4) ^ sw) * 8)];
    a = __builtin_amdgcn_mfma_f32_16x16x32_bf16(k0f, qf0, a, 0, 0, 0);
    a = __builtin_amdgcn_mfma_f32_16x16x32_bf16(k1f, qf1, a, 0, 0, 0);
    acc[st] = a;
  }

  // scalar row softmax: this lane's q-row is spread over hi4 groups (shfl 16,32)
  float mx = -1e30f;
#pragma unroll
  for (int st = 0; st < 32; ++st)
#pragma unroll
    for (int r = 0; r < 4; ++r) {
      acc[st][r] *= 0.125f;
      mx = fmaxf(mx, acc[st][r]);
    }
  mx = fmaxf(mx, __shfl_xor(mx, 16));
  mx = fmaxf(mx, __shfl_xor(mx, 32));
  float sm = 0.f;
#pragma unroll
  for (int st = 0; st < 32; ++st)
#pragma unroll
    for (int r = 0; r < 4; ++r) {
      const float e = __expf(acc[st][r] - mx);
      acc[st][r] = e;
      sm += e;
    }
  sm += __shfl_xor(sm, 16);
  sm += __shfl_xor(sm, 32);
  const float inv = 1.f / sm;

  __syncthreads();   // all waves done reading K tile; KP becomes the P buffer

  // V^T into LDS, swizzled (element idx ^ ((d&7)<<3)).
#pragma unroll
  for (int j = 0; j < 16; ++j) {
    const int d8 = j >> 1;
    const int s = (j & 1) * 256 + tid;
#pragma unroll
    for (int jj = 0; jj < 8; ++jj) {
      const int d = d8 * 8 + jj;
      VT[(d * 512 + s) ^ ((d & 7) << 3)] = ((const unsigned short*)&vreg[j])[jj];
    }
  }

  // normalize P in regs; bf16 P -> LDS (b64). Global stores deferred past barrier.
  const int q = wave * 16 + lo4;
#pragma unroll
  for (int st = 0; st < 32; ++st) {
    u16x4 pb;
#pragma unroll
    for (int r = 0; r < 4; ++r) {
      acc[st][r] *= inv;
      pb[r] = f2b_rn(acc[st][r]);
    }
    *(u16x4*)&KP[(q * 512 + st * 16 + hi4 * 4) ^ ((q & 7) << 3)] = pb;
  }
  __syncthreads();   // lgkm drain only matters; no outstanding global stores here

  // fp32 attn out now: stores drain under PV + next block's work, nothing waits.
  float* aout = attnf + (long)z * 262144 + (long)(q0 + q) * 512;
#pragma unroll
  for (int st = 0; st < 32; ++st)
    __builtin_nontemporal_store(acc[st], (f32x4*)(aout + st * 16 + hi4 * 4));

  // PV swapped: A = V^T (rows d), B = P (rows q) -> col=q, row=d.
  const int wq = (wave >> 1) * 32, wd = (wave & 1) * 32;
  f32x4 acc2[2][2] = {};
#pragma unroll
  for (int k0 = 0; k0 < 512; k0 += 32) {
    bf16x8 vf[2], pf[2];
#pragma unroll
    for (int mt = 0; mt < 2; ++mt) {
      const int d = wd + mt * 16 + lo4;
      vf[mt] = *(const bf16x8*)&VT[(d * 512 + k0 + hi4 * 8) ^ ((d & 7) << 3)];
    }
#pragma unroll
    for (int nt = 0; nt < 2; ++nt) {
      const int m = wq + nt * 16 + lo4;
      pf[nt] = *(const bf16x8*)&KP[(m * 512 + k0 + hi4 * 8) ^ ((m & 7) << 3)];
    }
#pragma unroll
    for (int mt = 0; mt < 2; ++mt)
#pragma unroll
      for (int nt = 0; nt < 2; ++nt)
        acc2[mt][nt] = __builtin_amdgcn_mfma_f32_16x16x32_bf16(vf[mt], pf[nt], acc2[mt][nt], 0, 0, 0);
  }

  // ctx write: col=q (lo4), row=d (hi4*4+r) -> u16x4 along d.
#pragma unroll
  for (int nt = 0; nt < 2; ++nt) {
    const int qq = q0 + wq + nt * 16 + lo4;
    unsigned short* cb = ctxb + ((long)(b * 512 + qq)) * 512 + h * 64;
#pragma unroll
    for (int mt = 0; mt < 2; ++mt) {
      u16x4 o;
#pragma unroll
      for (int r = 0; r < 4; ++r) o[r] = f2b_rn(acc2[mt][nt][r]);
      *(u16x4*)&cb[wd + mt * 16 + hi4 * 4] = o;
    }
  }
}

// out = LayerNorm(a + b) * g + be ; fp32 + bf16. Wave-per-row: 64 lanes x 8 elems,
// pure-shfl reduction (no LDS, no barrier). 4 rows per 256-thread block.
__global__ __launch_bounds__(256)
void resid_ln(const float* __restrict__ a, const float* __restrict__ b,
              const float* __restrict__ g, const float* __restrict__ be,
              float* __restrict__ outf, unsigned short* __restrict__ outb) {
  const int lane = threadIdx.x & 63;
  const long row = (long)blockIdx.x * 4 + (threadIdx.x >> 6);
  const long base = row * 512 + lane * 8;
  const f32x4 va0 = *(const f32x4*)&a[base];
  const f32x4 va1 = *(const f32x4*)&a[base + 4];
  const f32x4 vb0 = *(const f32x4*)&b[base];
  const f32x4 vb1 = *(const f32x4*)&b[base + 4];
  f32x4 v0, v1;
  float s = 0.f, s2 = 0.f;
#pragma unroll
  for (int i = 0; i < 4; ++i) {
    v0[i] = va0[i] + vb0[i]; s += v0[i]; s2 += v0[i] * v0[i];
    v1[i] = va1[i] + vb1[i]; s += v1[i]; s2 += v1[i] * v1[i];
  }
#pragma unroll
  for (int msk = 1; msk < 64; msk <<= 1) {
    s  += __shfl_xor(s, msk);
    s2 += __shfl_xor(s2, msk);
  }
  const float mu  = s * (1.f / 512.f);
  const float var = s2 * (1.f / 512.f) - mu * mu;
  const float ri  = rsqrtf(var + EPS_);
  const f32x4 vg0 = *(const f32x4*)&g[lane * 8];
  const f32x4 vg1 = *(const f32x4*)&g[lane * 8 + 4];
  const f32x4 ve0 = *(const f32x4*)&be[lane * 8];
  const f32x4 ve1 = *(const f32x4*)&be[lane * 8 + 4];
  f32x4 y0, y1;
  u16x4 yb0, yb1;
#pragma unroll
  for (int i = 0; i < 4; ++i) {
    y0[i] = (v0[i] - mu) * ri * vg0[i] + ve0[i]; yb0[i] = f2b_rn(y0[i]);
    y1[i] = (v1[i] - mu) * ri * vg1[i] + ve1[i]; yb1[i] = f2b_rn(y1[i]);
  }
  *(f32x4*)&outf[base]     = y0;
  *(f32x4*)&outf[base + 4] = y1;
  *(u16x4*)&outb[base]     = yb0;
  *(u16x4*)&outb[base + 4] = yb1;
}

// all four weight tensors fp32->bf16 in one launch (grid-stride over segments)
__global__ void f2b_all(const float* __restrict__ s0, unsigned short* __restrict__ d0, long n0,
                        const float* __restrict__ s1, unsigned short* __restrict__ d1, long n1,
                        const float* __restrict__ s2, unsigned short* __restrict__ d2, long n2,
                        const float* __restrict__ s3, unsigned short* __restrict__ d3, long n3) {
  const long total = n0 + n1 + n2 + n3;
  const long stride = (long)gridDim.x * 256;
  for (long i = (long)blockIdx.x * 256 + threadIdx.x; i < total; i += stride) {
    const float* s; unsigned short* d; long j = i;
    if (j < n0) { s = s0; d = d0; }
    else if ((j -= n0) < n1) { s = s1; d = d1; }
    else if ((j -= n1) < n2) { s = s2; d = d2; }
    else { j -= n2; s = s3; d = d3; }
    const f32x4 v = *(const f32x4*)&s[j * 4];
    u16x4 o;
#pragma unroll
    for (int k = 0; k < 4; ++k) o[k] = f2b_rn(v[k]);
    *(u16x4*)&d[j * 4] = o;
  }
}

__global__ void copy_conv(const float* __restrict__ in, float* __restrict__ outf,
                          unsigned short* __restrict__ outb, long n4) {
  long i = (long)blockIdx.x * 256 + threadIdx.x;
  const long stride = (long)gridDim.x * 256;
  for (; i < n4; i += stride) {
    const f32x4 v = *(const f32x4*)&in[i * 4];
    u16x4 o;
#pragma unroll
    for (int k = 0; k < 4; ++k) o[k] = f2b_rn(v[k]);
    *(f32x4*)&outf[i * 4] = v;
    *(u16x4*)&outb[i * 4] = o;
  }
}

extern "C" void kernel_launch(void* const* d_in, const int* in_sizes, int n_in,
                              void* d_out, int out_size, void* d_ws, size_t ws_size,
                              hipStream_t stream) {
  const float* src  = (const float*)d_in[0];
  const float* Wqkv = (const float*)d_in[1];
  const float* bqkv = (const float*)d_in[2];
  const float* Wo   = (const float*)d_in[3];
  const float* bo   = (const float*)d_in[4];
  const float* W1   = (const float*)d_in[5];
  const float* b1   = (const float*)d_in[6];
  const float* W2   = (const float*)d_in[7];
  const float* b2   = (const float*)d_in[8];
  const float* g1   = (const float*)d_in[9];
  const float* be1  = (const float*)d_in[10];
  const float* g2   = (const float*)d_in[11];
  const float* be2  = (const float*)d_in[12];

  char* p = (char*)d_ws;
  auto take = [&](size_t bytes) { void* r = (void*)p; p += (bytes + 255) & ~(size_t)255; return r; };
  float* x        = (float*)take((size_t)BL * 512 * 4);
  float* x1       = (float*)take((size_t)BL * 512 * 4);
  float* attn_out = (float*)take((size_t)BL * 512 * 4);
  float* ff2      = (float*)take((size_t)BL * 512 * 4);
  unsigned short* xbf    = (unsigned short*)take((size_t)BL * 512 * 2);
  unsigned short* qkvbf  = (unsigned short*)take((size_t)BL * 1536 * 2);
  unsigned short* ctxbf  = (unsigned short*)take((size_t)BL * 512 * 2);
  unsigned short* ff1bf  = (unsigned short*)take((size_t)BL * 2048 * 2);
  unsigned short* Wqkvb  = (unsigned short*)take((size_t)4 * 1536 * 512 * 2);
  unsigned short* Wob    = (unsigned short*)take((size_t)4 * 512 * 512 * 2);
  unsigned short* W1b    = (unsigned short*)take((size_t)4 * 2048 * 512 * 2);
  unsigned short* W2b    = (unsigned short*)take((size_t)4 * 512 * 2048 * 2);

  f2b_all<<<2048, 256, 0, stream>>>(
      Wqkv, Wqkvb, 4L * 1536 * 512 / 4,
      Wo,   Wob,   4L * 512 * 512 / 4,
      W1,   W1b,   4L * 2048 * 512 / 4,
      W2,   W2b,   4L * 512 * 2048 / 4);
  copy_conv<<<1024, 256, 0, stream>>>(src, x, xbf, (long)BL * 512 / 4);

  float* out_x    = (float*)d_out;
  float* out_attn = out_x + (size_t)BL * 512;

  for (int i = 0; i < NL_; ++i) {
    // QKV: [4096,1536] = x @ Wqkv^T + bqkv  (bf16 out); 64x128 tiles -> 768 blocks
    gemm_bt<64, 128, 2, 4><<<dim3(BL / 64, 1536 / 128, 1), 256, 0, stream>>>(
        xbf, 512, 0, 0, Wqkvb + (size_t)i * 1536 * 512, 512, 0, 0,
        nullptr, qkvbf, 1536, 0, 0, bqkv + (size_t)i * 1536, 512, 1.f, 0, 1);

    // fused scores+softmax+PV: fp32 attn -> d_out, ctx bf16 -> ctxbf
    float* attnL = out_attn + (size_t)i * 64 * 512 * 512;
    attn_fused<<<dim3(8, 64), 256, 0, stream>>>(qkvbf, attnL, ctxbf);

    // attn_out = ctx @ Wo^T + bo  (fp32)
    gemm_bt<128, 64, 4, 2><<<dim3(32, 8, 1), 256, 0, stream>>>(
        ctxbf, 512, 0, 0, Wob + (size_t)i * 512 * 512, 512, 0, 0,
        attn_out, nullptr, 512, 0, 0, bo + (size_t)i * 512, 512, 1.f, 0, 1);

    // x1 = LN(x + attn_out)
    resid_ln<<<BL / 4, 256, 0, stream>>>(x, attn_out, g1 + (size_t)i * 512,
                                         be1 + (size_t)i * 512, x1, xbf);

    // ff1 = relu(x1 @ W1^T + b1)  (bf16)
    gemm_bt<128, 128, 4, 4><<<dim3(32, 16, 1), 256, 0, stream>>>(
        xbf, 512, 0, 0, W1b + (size_t)i * 2048 * 512, 512, 0, 0,
        nullptr, ff1bf, 2048, 0, 0, b1 + (size_t)i * 2048, 512, 1.f, 1, 1);

    // ff2 = ff1 @ W2^T + b2  (fp32)
    gemm_bt<128, 64, 4, 2><<<dim3(32, 8, 1), 256, 0, stream>>>(
        ff1bf, 2048, 0, 0, W2b + (size_t)i * 512 * 2048, 2048, 0, 0,
        ff2, nullptr, 512, 0, 0, b2 + (size_t)i * 512, 2048, 1.f, 0, 1);

    // x = LN(x1 + ff2); final layer writes straight to d_out
    resid_ln<<<BL / 4, 256, 0, stream>>>(x1, ff2, g2 + (size_t)i * 512,
                                         be2 + (size_t)i * 512, (i == 3) ? out_x : x, xbf);
  }
}

// Round 6
// 745.687 us; speedup vs baseline: 1.2582x; 1.0596x over previous
//
// Round 8: GEMM K-step 32->64 (halves barriers, doubles per-stall MFMA coverage),
// XOR chunk-swizzled LDS tiles (pre-swizzled global source + swizzled ds_read,
// kills the 8/16-way b128 bank conflict), Wo/FF2 retiled 128x64 -> 64x64 so the
// grid gives 2 blocks/CU (co-resident block covers barrier stalls).
// Attn / LN / preamble unchanged from R7 (790us best).
#include <hip/hip_runtime.h>
#include <hip/hip_bf16.h>

#define B_ 8
#define L_ 512
#define D_ 512
#define H_ 8
#define F_ 2048
#define NL_ 4
#define BL 4096            // B_*L_
#define EPS_ 1e-5f

typedef __bf16 bf16_t;
typedef bf16_t bf16x8 __attribute__((ext_vector_type(8)));
typedef float f32x4 __attribute__((ext_vector_type(4)));
typedef unsigned short u16x4 __attribute__((ext_vector_type(4)));

__device__ __forceinline__ unsigned short f2b_rn(float f) {
  unsigned u = __builtin_bit_cast(unsigned, f);
  u = (u + 0x7fffu + ((u >> 16) & 1u)) >> 16;
  return (unsigned short)u;
}

// async global->LDS, 16B per lane. LDS dest must be wave-uniform base + lane*16.
__device__ __forceinline__ void gload_lds16(const unsigned short* g, unsigned short* l) {
  __builtin_amdgcn_global_load_lds(
      (const __attribute__((address_space(1))) void*)g,
      (__attribute__((address_space(3))) void*)l, 16, 0, 0);
}

// C[M,N] = relu?(scale * A[M,K] @ B[N,K]^T + bias[N]); optional fp32 and bf16 outputs.
// Batched via blockIdx.z with (z/zi, z%zi) stride decomposition for A/B/C.
// XCD-aware swizzle (z==1, gridX%8==0). 2-phase double-buffered pipeline, BK=64.
// LDS tiles are chunk-XOR-swizzled: LDS[r][chunk] = global[r][chunk ^ (r&7)]
// (linear LDS dest for global_load_lds, pre-swizzled SOURCE, swizzled read) so
// the row-strided ds_read_b128 fragment reads are 2-way (free) not 8/16-way.
// K must be a multiple of 64.
template<int BM, int BN, int MT, int NT>
__global__ __launch_bounds__(256)
void gemm_bt(const unsigned short* __restrict__ A, int lda, long sAo, long sAi,
             const unsigned short* __restrict__ Bm, int ldb, long sBo, long sBi,
             float* __restrict__ Cf, unsigned short* __restrict__ Cb, int ldc,
             long sCo, long sCi,
             const float* __restrict__ bias, int K, float scale, int relu, int zi)
{
  static_assert(BM == MT * 32 && BN == NT * 32, "waves are 2x2");
  __shared__ __align__(16) unsigned short As[2][BM * 64];
  __shared__ __align__(16) unsigned short Bs[2][BN * 64];
  const int tid  = threadIdx.x;
  const int lane = tid & 63;
  const int wave = tid >> 6;
  const int lo4 = lane & 15, hi4 = lane >> 4;
  const int wm = (wave >> 1) * (MT * 16);
  const int wn = (wave & 1) * (NT * 16);
  int bx = blockIdx.x, by = blockIdx.y;
  if (gridDim.z == 1 && (gridDim.x & 7) == 0) {
    const int gx = gridDim.x, cx = gx >> 3;
    const int lid = by * gx + bx;
    const int xcd = lid & 7;
    const int t = lid >> 3;
    bx = xcd * cx + (t % cx);
    by = t / cx;
  }
  const int m0 = bx * BM;
  const int n0 = by * BN;
  const int z  = blockIdx.z;
  const long offA = (long)(z / zi) * sAo + (long)(z % zi) * sAi;
  const long offB = (long)(z / zi) * sBo + (long)(z % zi) * sBi;
  const long offC = (long)(z / zi) * sCo + (long)(z % zi) * sCi;

  const unsigned short* Ab = A + offA + (long)m0 * lda;
  const unsigned short* Bb = Bm + offB + (long)n0 * ldb;

  // rows hold 64 elems = 8 chunks of 8; source chunk pre-swizzled by row&7.
  auto stage = [&](int buf, int k0) {
#pragma unroll
    for (int j = 0; j < BM / 32; ++j) {
      int c = tid + j * 256;
      int r = c >> 3, ch = (c & 7) ^ (r & 7);
      gload_lds16(Ab + (long)r * lda + (k0 + ch * 8), &As[buf][c * 8]);
    }
#pragma unroll
    for (int j = 0; j < BN / 32; ++j) {
      int c = tid + j * 256;
      int r = c >> 3, ch = (c & 7) ^ (r & 7);
      gload_lds16(Bb + (long)r * ldb + (k0 + ch * 8), &Bs[buf][c * 8]);
    }
  };

  f32x4 acc[MT][NT] = {};

  stage(0, 0);
  __syncthreads();
  int cur = 0;
  const int sw = lane & 7;          // row&7 for fragment rows (wm/wn mult of 16)
  for (int k0 = 0; k0 < K; k0 += 64) {
    if (k0 + 64 < K) stage(cur ^ 1, k0 + 64);   // prefetch next tile (async)
#pragma unroll
    for (int kc = 0; kc < 2; ++kc) {
      const int ch = ((kc * 4 + hi4) ^ sw) * 8;
      bf16x8 af[MT], bfr[NT];
#pragma unroll
      for (int mt = 0; mt < MT; ++mt)
        af[mt] = *(const bf16x8*)(&As[cur][(wm + mt * 16 + lo4) * 64 + ch]);
#pragma unroll
      for (int nt = 0; nt < NT; ++nt)
        bfr[nt] = *(const bf16x8*)(&Bs[cur][(wn + nt * 16 + lo4) * 64 + ch]);
#pragma unroll
      for (int mt = 0; mt < MT; ++mt)
#pragma unroll
        for (int nt = 0; nt < NT; ++nt)
          acc[mt][nt] = __builtin_amdgcn_mfma_f32_16x16x32_bf16(af[mt], bfr[nt], acc[mt][nt], 0, 0, 0);
    }
    __syncthreads();   // drains prefetch (overlapped with MFMA) + guards buffer swap
    cur ^= 1;
  }

  // C/D layout: col=lane&15, row=(lane>>4)*4+r
#pragma unroll
  for (int nt = 0; nt < NT; ++nt) {
    const int col = n0 + wn + nt * 16 + lo4;
    const float bb = bias ? bias[col] : 0.f;
#pragma unroll
    for (int mt = 0; mt < MT; ++mt) {
#pragma unroll
      for (int r = 0; r < 4; ++r) {
        const int row = m0 + wm + mt * 16 + hi4 * 4 + r;
        float v = acc[mt][nt][r] * scale + bb;
        if (relu) v = fmaxf(v, 0.f);
        const long o = offC + (long)row * ldc + col;
        if (Cf) Cf[o] = v;
        if (Cb) Cb[o] = f2b_rn(v);
      }
    }
  }
}

// Fused attention, swapped operands. Per (64-row q-block, z=(b*8+h)):
//   scores^T = mfma(K,Q) -> scalar softmax (lane owns one q-row) -> P (bf16) into
//   LDS + V^T into LDS -> barrier -> coalesced f32x4 nontemporal attn stores
//   (AFTER the barrier: drain overlaps PV) -> ctx^T = mfma(V^T,P) -> u16x4 ctx.
__global__ __launch_bounds__(256)
void attn_fused(const unsigned short* __restrict__ qkv,
                float* __restrict__ attnf,
                unsigned short* __restrict__ ctxb) {
  __shared__ __align__(16) unsigned short Qs[64 * 64];    // 8 KB, linear
  __shared__ __align__(16) unsigned short KP[512 * 64];   // 64 KB: K (src-preswizzled) then P (swizzled)
  __shared__ __align__(16) unsigned short VT[64 * 512];   // 64 KB: V^T (swizzled)
  const int tid = threadIdx.x, lane = tid & 63, wave = tid >> 6;
  const int lo4 = lane & 15, hi4 = lane >> 4;
  // XCD remap: each XCD owns 8 consecutive (b,h) groups -> K/V L2-resident.
  int bxr = blockIdx.x, byr = blockIdx.y;
  {
    const int lid = byr * 8 + bxr;           // grid is (8, 64)
    const int xcd = lid & 7;
    const int t = lid >> 3;                  // [0,64)
    byr = xcd * 8 + (t & 7);
    bxr = t >> 3;
  }
  const int q0 = bxr * 64;
  const int z = byr, b = z >> 3, h = z & 7;
  const unsigned short* qbase = qkv + (long)b * 512 * 1536 + h * 64;
  const unsigned short* kbase = qbase + 512;
  const unsigned short* vbase = qbase + 1024;

  // V prefetch into regs: 16 x 16B per thread (drained by barrier-1 vmcnt(0)).
  bf16x8 vreg[16];
#pragma unroll
  for (int j = 0; j < 16; ++j) {
    const int d8 = j >> 1;
    const int s = (j & 1) * 256 + tid;
    vreg[j] = *(const bf16x8*)(vbase + (long)s * 1536 + d8 * 8);
  }

  // stage Q [64,64] linear
#pragma unroll
  for (int j = 0; j < 2; ++j) {
    int c = tid + j * 256;
    int r = c >> 3, cc = (c & 7) * 8;
    gload_lds16(qbase + (long)(q0 + r) * 1536 + cc, &Qs[c * 8]);
  }
  // stage K [512,64] with pre-swizzled SOURCE (linear LDS dest + swizzled read)
#pragma unroll
  for (int j = 0; j < 16; ++j) {
    int c = tid + j * 256;
    int r = c >> 3, ch = (c & 7) ^ (r & 7);
    gload_lds16(kbase + (long)r * 1536 + ch * 8, &KP[c * 8]);
  }
  __syncthreads();

  // Q fragments (B operand): row n = q = wave*16 + lo4
  const bf16x8 qf0 = *(const bf16x8*)&Qs[(wave * 16 + lo4) * 64 + hi4 * 8];
  const bf16x8 qf1 = *(const bf16x8*)&Qs[(wave * 16 + lo4) * 64 + 32 + hi4 * 8];

  // scores^T: acc[st] holds col=q (this lane's row), row = s = st*16 + hi4*4 + r
  f32x4 acc[32];
#pragma unroll
  for (int st = 0; st < 32; ++st) {
    const int n = st * 16 + lo4;
    const int sw = lo4 & 7;
    f32x4 a = {};
    const bf16x8 k0f = *(const bf16x8*)&KP[n * 64 + ((hi4 ^ sw) * 8)];
    const bf16x8 k1f = *(const bf16x8*)&KP[n * 64 + (((hi4 + 4) ^ sw) * 8)];
    a = __builtin_amdgcn_mfma_f32_16x16x32_bf16(k0f, qf0, a, 0, 0, 0);
    a = __builtin_amdgcn_mfma_f32_16x16x32_bf16(k1f, qf1, a, 0, 0, 0);
    acc[st] = a;
  }

  // scalar row softmax: this lane's q-row is spread over hi4 groups (shfl 16,32)
  float mx = -1e30f;
#pragma unroll
  for (int st = 0; st < 32; ++st)
#pragma unroll
    for (int r = 0; r < 4; ++r) {
      acc[st][r] *= 0.125f;
      mx = fmaxf(mx, acc[st][r]);
    }
  mx = fmaxf(mx, __shfl_xor(mx, 16));
  mx = fmaxf(mx, __shfl_xor(mx, 32));
  float sm = 0.f;
#pragma unroll
  for (int st = 0; st < 32; ++st)
#pragma unroll
    for (int r = 0; r < 4; ++r) {
      const float e = __expf(acc[st][r] - mx);
      acc[st][r] = e;
      sm += e;
    }
  sm += __shfl_xor(sm, 16);
  sm += __shfl_xor(sm, 32);
  const float inv = 1.f / sm;

  __syncthreads();   // all waves done reading K tile; KP becomes the P buffer

  // V^T into LDS, swizzled (element idx ^ ((d&7)<<3)).
#pragma unroll
  for (int j = 0; j < 16; ++j) {
    const int d8 = j >> 1;
    const int s = (j & 1) * 256 + tid;
#pragma unroll
    for (int jj = 0; jj < 8; ++jj) {
      const int d = d8 * 8 + jj;
      VT[(d * 512 + s) ^ ((d & 7) << 3)] = ((const unsigned short*)&vreg[j])[jj];
    }
  }

  // normalize P in regs; bf16 P -> LDS (b64). Global stores deferred past barrier.
  const int q = wave * 16 + lo4;
#pragma unroll
  for (int st = 0; st < 32; ++st) {
    u16x4 pb;
#pragma unroll
    for (int r = 0; r < 4; ++r) {
      acc[st][r] *= inv;
      pb[r] = f2b_rn(acc[st][r]);
    }
    *(u16x4*)&KP[(q * 512 + st * 16 + hi4 * 4) ^ ((q & 7) << 3)] = pb;
  }
  __syncthreads();   // lgkm drain only matters; no outstanding global stores here

  // fp32 attn out now: stores drain under PV + next block's work, nothing waits.
  float* aout = attnf + (long)z * 262144 + (long)(q0 + q) * 512;
#pragma unroll
  for (int st = 0; st < 32; ++st)
    __builtin_nontemporal_store(acc[st], (f32x4*)(aout + st * 16 + hi4 * 4));

  // PV swapped: A = V^T (rows d), B = P (rows q) -> col=q, row=d.
  const int wq = (wave >> 1) * 32, wd = (wave & 1) * 32;
  f32x4 acc2[2][2] = {};
#pragma unroll
  for (int k0 = 0; k0 < 512; k0 += 32) {
    bf16x8 vf[2], pf[2];
#pragma unroll
    for (int mt = 0; mt < 2; ++mt) {
      const int d = wd + mt * 16 + lo4;
      vf[mt] = *(const bf16x8*)&VT[(d * 512 + k0 + hi4 * 8) ^ ((d & 7) << 3)];
    }
#pragma unroll
    for (int nt = 0; nt < 2; ++nt) {
      const int m = wq + nt * 16 + lo4;
      pf[nt] = *(const bf16x8*)&KP[(m * 512 + k0 + hi4 * 8) ^ ((m & 7) << 3)];
    }
#pragma unroll
    for (int mt = 0; mt < 2; ++mt)
#pragma unroll
      for (int nt = 0; nt < 2; ++nt)
        acc2[mt][nt] = __builtin_amdgcn_mfma_f32_16x16x32_bf16(vf[mt], pf[nt], acc2[mt][nt], 0, 0, 0);
  }

  // ctx write: col=q (lo4), row=d (hi4*4+r) -> u16x4 along d.
#pragma unroll
  for (int nt = 0; nt < 2; ++nt) {
    const int qq = q0 + wq + nt * 16 + lo4;
    unsigned short* cb = ctxb + ((long)(b * 512 + qq)) * 512 + h * 64;
#pragma unroll
    for (int mt = 0; mt < 2; ++mt) {
      u16x4 o;
#pragma unroll
      for (int r = 0; r < 4; ++r) o[r] = f2b_rn(acc2[mt][nt][r]);
      *(u16x4*)&cb[wd + mt * 16 + hi4 * 4] = o;
    }
  }
}

// out = LayerNorm(a + b) * g + be ; fp32 + bf16. Wave-per-row: 64 lanes x 8 elems,
// pure-shfl reduction (no LDS, no barrier). 4 rows per 256-thread block.
__global__ __launch_bounds__(256)
void resid_ln(const float* __restrict__ a, const float* __restrict__ b,
              const float* __restrict__ g, const float* __restrict__ be,
              float* __restrict__ outf, unsigned short* __restrict__ outb) {
  const int lane = threadIdx.x & 63;
  const long row = (long)blockIdx.x * 4 + (threadIdx.x >> 6);
  const long base = row * 512 + lane * 8;
  const f32x4 va0 = *(const f32x4*)&a[base];
  const f32x4 va1 = *(const f32x4*)&a[base + 4];
  const f32x4 vb0 = *(const f32x4*)&b[base];
  const f32x4 vb1 = *(const f32x4*)&b[base + 4];
  f32x4 v0, v1;
  float s = 0.f, s2 = 0.f;
#pragma unroll
  for (int i = 0; i < 4; ++i) {
    v0[i] = va0[i] + vb0[i]; s += v0[i]; s2 += v0[i] * v0[i];
    v1[i] = va1[i] + vb1[i]; s += v1[i]; s2 += v1[i] * v1[i];
  }
#pragma unroll
  for (int msk = 1; msk < 64; msk <<= 1) {
    s  += __shfl_xor(s, msk);
    s2 += __shfl_xor(s2, msk);
  }
  const float mu  = s * (1.f / 512.f);
  const float var = s2 * (1.f / 512.f) - mu * mu;
  const float ri  = rsqrtf(var + EPS_);
  const f32x4 vg0 = *(const f32x4*)&g[lane * 8];
  const f32x4 vg1 = *(const f32x4*)&g[lane * 8 + 4];
  const f32x4 ve0 = *(const f32x4*)&be[lane * 8];
  const f32x4 ve1 = *(const f32x4*)&be[lane * 8 + 4];
  f32x4 y0, y1;
  u16x4 yb0, yb1;
#pragma unroll
  for (int i = 0; i < 4; ++i) {
    y0[i] = (v0[i] - mu) * ri * vg0[i] + ve0[i]; yb0[i] = f2b_rn(y0[i]);
    y1[i] = (v1[i] - mu) * ri * vg1[i] + ve1[i]; yb1[i] = f2b_rn(y1[i]);
  }
  *(f32x4*)&outf[base]     = y0;
  *(f32x4*)&outf[base + 4] = y1;
  *(u16x4*)&outb[base]     = yb0;
  *(u16x4*)&outb[base + 4] = yb1;
}

// all four weight tensors fp32->bf16 in one launch (grid-stride over segments)
__global__ void f2b_all(const float* __restrict__ s0, unsigned short* __restrict__ d0, long n0,
                        const float* __restrict__ s1, unsigned short* __restrict__ d1, long n1,
                        const float* __restrict__ s2, unsigned short* __restrict__ d2, long n2,
                        const float* __restrict__ s3, unsigned short* __restrict__ d3, long n3) {
  const long total = n0 + n1 + n2 + n3;
  const long stride = (long)gridDim.x * 256;
  for (long i = (long)blockIdx.x * 256 + threadIdx.x; i < total; i += stride) {
    const float* s; unsigned short* d; long j = i;
    if (j < n0) { s = s0; d = d0; }
    else if ((j -= n0) < n1) { s = s1; d = d1; }
    else if ((j -= n1) < n2) { s = s2; d = d2; }
    else { j -= n2; s = s3; d = d3; }
    const f32x4 v = *(const f32x4*)&s[j * 4];
    u16x4 o;
#pragma unroll
    for (int k = 0; k < 4; ++k) o[k] = f2b_rn(v[k]);
    *(u16x4*)&d[j * 4] = o;
  }
}

__global__ void copy_conv(const float* __restrict__ in, float* __restrict__ outf,
                          unsigned short* __restrict__ outb, long n4) {
  long i = (long)blockIdx.x * 256 + threadIdx.x;
  const long stride = (long)gridDim.x * 256;
  for (; i < n4; i += stride) {
    const f32x4 v = *(const f32x4*)&in[i * 4];
    u16x4 o;
#pragma unroll
    for (int k = 0; k < 4; ++k) o[k] = f2b_rn(v[k]);
    *(f32x4*)&outf[i * 4] = v;
    *(u16x4*)&outb[i * 4] = o;
  }
}

extern "C" void kernel_launch(void* const* d_in, const int* in_sizes, int n_in,
                              void* d_out, int out_size, void* d_ws, size_t ws_size,
                              hipStream_t stream) {
  const float* src  = (const float*)d_in[0];
  const float* Wqkv = (const float*)d_in[1];
  const float* bqkv = (const float*)d_in[2];
  const float* Wo   = (const float*)d_in[3];
  const float* bo   = (const float*)d_in[4];
  const float* W1   = (const float*)d_in[5];
  const float* b1   = (const float*)d_in[6];
  const float* W2   = (const float*)d_in[7];
  const float* b2   = (const float*)d_in[8];
  const float* g1   = (const float*)d_in[9];
  const float* be1  = (const float*)d_in[10];
  const float* g2   = (const float*)d_in[11];
  const float* be2  = (const float*)d_in[12];

  char* p = (char*)d_ws;
  auto take = [&](size_t bytes) { void* r = (void*)p; p += (bytes + 255) & ~(size_t)255; return r; };
  float* x        = (float*)take((size_t)BL * 512 * 4);
  float* x1       = (float*)take((size_t)BL * 512 * 4);
  float* attn_out = (float*)take((size_t)BL * 512 * 4);
  float* ff2      = (float*)take((size_t)BL * 512 * 4);
  unsigned short* xbf    = (unsigned short*)take((size_t)BL * 512 * 2);
  unsigned short* qkvbf  = (unsigned short*)take((size_t)BL * 1536 * 2);
  unsigned short* ctxbf  = (unsigned short*)take((size_t)BL * 512 * 2);
  unsigned short* ff1bf  = (unsigned short*)take((size_t)BL * 2048 * 2);
  unsigned short* Wqkvb  = (unsigned short*)take((size_t)4 * 1536 * 512 * 2);
  unsigned short* Wob    = (unsigned short*)take((size_t)4 * 512 * 512 * 2);
  unsigned short* W1b    = (unsigned short*)take((size_t)4 * 2048 * 512 * 2);
  unsigned short* W2b    = (unsigned short*)take((size_t)4 * 512 * 2048 * 2);

  f2b_all<<<2048, 256, 0, stream>>>(
      Wqkv, Wqkvb, 4L * 1536 * 512 / 4,
      Wo,   Wob,   4L * 512 * 512 / 4,
      W1,   W1b,   4L * 2048 * 512 / 4,
      W2,   W2b,   4L * 512 * 2048 / 4);
  copy_conv<<<1024, 256, 0, stream>>>(src, x, xbf, (long)BL * 512 / 4);

  float* out_x    = (float*)d_out;
  float* out_attn = out_x + (size_t)BL * 512;

  for (int i = 0; i < NL_; ++i) {
    // QKV: [4096,1536] = x @ Wqkv^T + bqkv  (bf16 out); 64x128 tiles -> 768 blocks
    gemm_bt<64, 128, 2, 4><<<dim3(BL / 64, 1536 / 128, 1), 256, 0, stream>>>(
        xbf, 512, 0, 0, Wqkvb + (size_t)i * 1536 * 512, 512, 0, 0,
        nullptr, qkvbf, 1536, 0, 0, bqkv + (size_t)i * 1536, 512, 1.f, 0, 1);

    // fused scores+softmax+PV: fp32 attn -> d_out, ctx bf16 -> ctxbf
    float* attnL = out_attn + (size_t)i * 64 * 512 * 512;
    attn_fused<<<dim3(8, 64), 256, 0, stream>>>(qkvbf, attnL, ctxbf);

    // attn_out = ctx @ Wo^T + bo  (fp32); 64x64 tiles -> 512 blocks = 2/CU
    gemm_bt<64, 64, 2, 2><<<dim3(64, 8, 1), 256, 0, stream>>>(
        ctxbf, 512, 0, 0, Wob + (size_t)i * 512 * 512, 512, 0, 0,
        attn_out, nullptr, 512, 0, 0, bo + (size_t)i * 512, 512, 1.f, 0, 1);

    // x1 = LN(x + attn_out)
    resid_ln<<<BL / 4, 256, 0, stream>>>(x, attn_out, g1 + (size_t)i * 512,
                                         be1 + (size_t)i * 512, x1, xbf);

    // ff1 = relu(x1 @ W1^T + b1)  (bf16); 128x128 tiles -> 512 blocks = 2/CU
    gemm_bt<128, 128, 4, 4><<<dim3(32, 16, 1), 256, 0, stream>>>(
        xbf, 512, 0, 0, W1b + (size_t)i * 2048 * 512, 512, 0, 0,
        nullptr, ff1bf, 2048, 0, 0, b1 + (size_t)i * 2048, 512, 1.f, 1, 1);

    // ff2 = ff1 @ W2^T + b2  (fp32); 64x64 tiles -> 512 blocks = 2/CU
    gemm_bt<64, 64, 2, 2><<<dim3(64, 8, 1), 256, 0, stream>>>(
        ff1bf, 2048, 0, 0, W2b + (size_t)i * 512 * 2048, 2048, 0, 0,
        ff2, nullptr, 512, 0, 0, b2 + (size_t)i * 512, 2048, 1.f, 0, 1);

    // x = LN(x1 + ff2); final layer writes straight to d_out
    resid_ln<<<BL / 4, 256, 0, stream>>>(x1, ff2, g2 + (size_t)i * 512,
                                         be2 + (size_t)i * 512, (i == 3) ? out_x : x, xbf);
  }
}